// Round 8
// baseline (555.867 us; speedup 1.0000x reference)
//
#include <hip/hip_runtime.h>

#define HH 128
#define BN_EPS 1e-5f

typedef __attribute__((ext_vector_type(8))) short short8;
typedef __attribute__((ext_vector_type(4))) float floatx4;

__device__ inline void atomAddF(float* p, float v) { unsafeAtomicAdd(p, v); }

__device__ inline short8 mk8(uint a, uint b, uint c, uint d) {
    union { uint u[4]; short8 s; } t;
    t.u[0] = a; t.u[1] = b; t.u[2] = c; t.u[3] = d;
    return t.s;
}

__device__ inline ushort f2bf(float f) {
    uint u = __float_as_uint(f);
    u = u + 0x7FFFu + ((u >> 16) & 1u);
    return (ushort)(u >> 16);
}

__device__ inline float bfLo(uint u) { return __uint_as_float(u << 16); }
__device__ inline float bfHi(uint u) { return __uint_as_float(u & 0xFFFF0000u); }

__device__ inline void splitPair(float f0, float f1, uint& hw, uint& lw) {
    uint u0 = __float_as_uint(f0), u1 = __float_as_uint(f1);
    hw = __builtin_amdgcn_perm(u1, u0, 0x07060302);
    float r0 = f0 - __uint_as_float(u0 & 0xFFFF0000u);
    float r1 = f1 - __uint_as_float(u1 & 0xFFFF0000u);
    lw = __builtin_amdgcn_perm(__float_as_uint(r1), __float_as_uint(r0), 0x07060302);
}

// ================= CSR build via 2-level bucket sort (NO global atomics) ====

__global__ __launch_bounds__(256) void k_ahist(const int* __restrict__ dst,
                                               int* __restrict__ gH, int E, int tile) {
    __shared__ int hist[256];
    int b = blockIdx.x, tid = threadIdx.x;
    hist[tid] = 0;
    __syncthreads();
    int s0 = b * tile, s1 = min(s0 + tile, E);
    for (int i = s0 + tid; i < s1; i += 256)
        atomicAdd(&hist[((unsigned)dst[i]) >> 8], 1);
    __syncthreads();
    gH[tid * 256 + b] = hist[tid];
}

__global__ __launch_bounds__(256) void k_scan1(const int* __restrict__ gH,
                                               int* __restrict__ gC,
                                               int* __restrict__ totals) {
    __shared__ int s[256];
    int h = blockIdx.x, b = threadIdx.x;
    int v = gH[h * 256 + b];
    s[b] = v;
    __syncthreads();
    for (int off = 1; off < 256; off <<= 1) {
        int t = (b >= off) ? s[b - off] : 0;
        __syncthreads();
        s[b] += t;
        __syncthreads();
    }
    gC[h * 256 + b] = s[b] - v;
    if (b == 255) totals[h] = s[255];
}

__global__ __launch_bounds__(256) void k_scan2(const int* __restrict__ totals,
                                               int* __restrict__ base) {
    __shared__ int s[256];
    int tid = threadIdx.x;
    int v = totals[tid];
    s[tid] = v;
    __syncthreads();
    for (int off = 1; off < 256; off <<= 1) {
        int t = (tid >= off) ? s[tid - off] : 0;
        __syncthreads();
        s[tid] += t;
        __syncthreads();
    }
    base[tid] = s[tid] - v;
    if (tid == 255) base[256] = s[255];
}

__global__ __launch_bounds__(256) void k_asc(const int* __restrict__ src,
                                             const int* __restrict__ dst,
                                             const int* __restrict__ gC,
                                             const int* __restrict__ base,
                                             uint2* __restrict__ bucketed,
                                             int E, int tile) {
    __shared__ int cur[256];
    int b = blockIdx.x, tid = threadIdx.x;
    cur[tid] = gC[tid * 256 + b] + base[tid];
    __syncthreads();
    int s0 = b * tile, s1 = min(s0 + tile, E);
    for (int i = s0 + tid; i < s1; i += 256) {
        int d = dst[i];
        int pos = atomicAdd(&cur[((unsigned)d) >> 8], 1);
        bucketed[pos] = make_uint2((uint)src[i], (uint)d);
    }
}

__global__ __launch_bounds__(256) void k_bdeg(const uint2* __restrict__ bucketed,
                                              const int* __restrict__ base,
                                              int* __restrict__ degInt,
                                              float* __restrict__ dinv, int N) {
    __shared__ int hist[256];
    int h = blockIdx.x, tid = threadIdx.x;
    hist[tid] = 0;
    __syncthreads();
    int s0 = base[h], s1 = base[h + 1];
    for (int i = s0 + tid; i < s1; i += 256)
        atomicAdd(&hist[bucketed[i].y & 255u], 1);
    __syncthreads();
    int n = h * 256 + tid;
    if (n < N) {
        int d = hist[tid];
        degInt[n] = d;
        dinv[n] = rsqrtf((float)d + 1.0f);
    }
}

__global__ __launch_bounds__(256) void k_scanA(const int* __restrict__ degInt,
                                               int* __restrict__ partials, int N) {
    __shared__ int s[256];
    int i = blockIdx.x * 256 + threadIdx.x;
    int d = (i < N) ? degInt[i] : 0;
    s[threadIdx.x] = d;
    __syncthreads();
    for (int off = 128; off > 0; off >>= 1) {
        if (threadIdx.x < off) s[threadIdx.x] += s[threadIdx.x + off];
        __syncthreads();
    }
    if (threadIdx.x == 0) partials[blockIdx.x] = s[0];
}

__global__ __launch_bounds__(256) void k_scanB(int* __restrict__ partials, int nb) {
    __shared__ int s[256];
    int tid = threadIdx.x;
    int v = (tid < nb) ? partials[tid] : 0;
    s[tid] = v;
    __syncthreads();
    for (int off = 1; off < 256; off <<= 1) {
        int t = (tid >= off) ? s[tid - off] : 0;
        __syncthreads();
        s[tid] += t;
        __syncthreads();
    }
    partials[tid] = s[tid] - v;
}

__global__ __launch_bounds__(256) void k_scanC(const int* __restrict__ degInt,
                                               const int* __restrict__ partials,
                                               int* __restrict__ rowptr, int N) {
    __shared__ int s[256];
    int tid = threadIdx.x;
    int i = blockIdx.x * 256 + tid;
    int d = (i < N) ? degInt[i] : 0;
    s[tid] = d;
    __syncthreads();
    for (int off = 1; off < 256; off <<= 1) {
        int t = (tid >= off) ? s[tid - off] : 0;
        __syncthreads();
        s[tid] += t;
        __syncthreads();
    }
    int incl = s[tid];
    int b = partials[blockIdx.x];
    if (i < N) {
        rowptr[i] = b + incl - d;
        if (i == N - 1) rowptr[N] = b + incl;
    }
}

__global__ __launch_bounds__(256) void k_csc(const uint2* __restrict__ bucketed,
                                             const int* __restrict__ base,
                                             const int* __restrict__ rowptr,
                                             int* __restrict__ csr_src, int N) {
    __shared__ int cur[256];
    int h = blockIdx.x, tid = threadIdx.x;
    int n = h * 256 + tid;
    cur[tid] = (n < N) ? rowptr[n] : 0;
    __syncthreads();
    int s0 = base[h], s1 = base[h + 1];
    for (int i = s0 + tid; i < s1; i += 256) {
        uint2 e = bucketed[i];
        int pos = atomicAdd(&cur[e.y & 255u], 1);
        csr_src[pos] = (int)e.x;
    }
}

// ---------- W split ----------
__global__ void k_wsplit(const float* __restrict__ W, uint* __restrict__ Wp, int K) {
    int t = blockIdx.x * 256 + threadIdx.x;
    int half = K >> 1;
    if (t >= 128 * half) return;
    int n = t / half;
    int p = t - n * half;
    uint hw, lw;
    splitPair(W[(2 * p) * HH + n], W[(2 * p + 1) * HH + n], hw, lw);
    Wp[n * K + 2 * p]     = hw;
    Wp[n * K + 2 * p + 1] = lw;
}

// ---------- MFMA GEMM: A[N,K] fp32 @ W[K,128] -> out bf16 QUARTER-MAJOR ----
// out layout: 4 planes of [N][32 cols] bf16 (plane = col/32), so k_agg's
// per-XCD quarter gather has a contiguous 3.2MB working set (fits 4MiB L2).
template<int KT>   // K = KT*32
__global__ __launch_bounds__(256) void k_gemm_mfma(const float* __restrict__ A,
                                                   const uint* __restrict__ Wp,
                                                   ushort* __restrict__ out,
                                                   int N) {
    const int K = KT * 32;
    const int NCH = KT / 2;
    __shared__ uint Bs[128 * 68];
    int tid  = threadIdx.x;
    int wave = tid >> 6;
    int lane = tid & 63;
    int m16  = lane & 15;
    int quad = lane >> 4;
    int row  = blockIdx.x * 64 + wave * 16 + m16;
    int rowc = min(row, N - 1);

    const float4* a4 = (const float4*)(A + (size_t)rowc * K);
    float4 araw[2 * KT];
#pragma unroll
    for (int kt = 0; kt < KT; kt++) {
        araw[2 * kt]     = a4[kt * 8 + quad * 2];
        araw[2 * kt + 1] = a4[kt * 8 + quad * 2 + 1];
    }

    floatx4 acc[8];
#pragma unroll
    for (int c = 0; c < 8; c++) acc[c] = (floatx4){0.f, 0.f, 0.f, 0.f};

    int sn0 = tid >> 4;
    int sq4 = tid & 15;

    for (int ch = 0; ch < NCH; ch++) {
#pragma unroll
        for (int i = 0; i < 8; i++) {
            int n = i * 16 + sn0;
            *(uint4*)&Bs[n * 68 + sq4 * 4] =
                *(const uint4*)&Wp[(size_t)n * K + ch * 64 + sq4 * 4];
        }
        __syncthreads();

#pragma unroll
        for (int ktl = 0; ktl < 2; ktl++) {
            int ktg = ch * 2 + ktl;
            float4 f0 = araw[2 * ktg];
            float4 f1 = araw[2 * ktg + 1];
            uint ahw[4], alw[4];
            splitPair(f0.x, f0.y, ahw[0], alw[0]);
            splitPair(f0.z, f0.w, ahw[1], alw[1]);
            splitPair(f1.x, f1.y, ahw[2], alw[2]);
            splitPair(f1.z, f1.w, ahw[3], alw[3]);
            short8 a_hi = mk8(ahw[0], ahw[1], ahw[2], ahw[3]);
            short8 a_lo = mk8(alw[0], alw[1], alw[2], alw[3]);

#pragma unroll
            for (int c = 0; c < 8; c++) {
                const uint* bp = &Bs[(c * 16 + m16) * 68 + ktl * 32 + quad * 8];
                uint4 w0 = *(const uint4*)bp;
                uint4 w1 = *(const uint4*)(bp + 4);
                short8 b_hi = mk8(w0.x, w0.z, w1.x, w1.z);
                short8 b_lo = mk8(w0.y, w0.w, w1.y, w1.w);
                acc[c] = __builtin_amdgcn_mfma_f32_16x16x32_bf16(a_hi, b_hi, acc[c], 0, 0, 0);
                acc[c] = __builtin_amdgcn_mfma_f32_16x16x32_bf16(a_lo, b_hi, acc[c], 0, 0, 0);
                acc[c] = __builtin_amdgcn_mfma_f32_16x16x32_bf16(a_hi, b_lo, acc[c], 0, 0, 0);
            }
        }
        __syncthreads();
    }

    int rowbase = blockIdx.x * 64 + wave * 16 + quad * 4;
#pragma unroll
    for (int c = 0; c < 8; c++) {
        size_t plane = (size_t)(c >> 1) * N;
        int off = (c & 1) * 16 + m16;
#pragma unroll
        for (int r = 0; r < 4; r++) {
            int rr = rowbase + r;
            if (rr < N) out[(plane + rr) * 32 + off] = f2bf(acc[c][r]);
        }
    }
}

// ---------- CSR aggregation: quarter-column partitioned, XCD-affine --------
// block -> (node group of 4, col-quarter q); q = blockIdx%4 and XCD = blockIdx%8
// so each XCD gathers (mostly) one 3.2MB plane -> L2-resident.
// wave per node: 16 edge phases x 4 lanes x 16B (8 bf16 cols per lane).
__global__ __launch_bounds__(256) void k_agg(const ushort* __restrict__ xwb,
                                             const float* __restrict__ dinv,
                                             const int* __restrict__ rowptr,
                                             const int* __restrict__ csr_src,
                                             const float* __restrict__ b,
                                             const float* __restrict__ g,
                                             const float* __restrict__ beta,
                                             const float* __restrict__ m,
                                             const float* __restrict__ v,
                                             float* __restrict__ out,
                                             int N, int mode) {
    __shared__ int   sS[256];
    __shared__ float sD[256];
    int gid = blockIdx.x;
    int q    = gid & 3;               // col-quarter (== XCD%4 under %8 swizzle)
    int par  = (gid >> 2) & 1;
    int ngrp = (gid >> 3) * 2 + par;
    int wave = threadIdx.x >> 6;
    int lane = threadIdx.x & 63;
    int n = ngrp * 4 + wave;
    if (n >= N) return;
    int wbase = wave * 64;
    int p  = lane >> 2;               // edge phase 0..15
    int c4 = lane & 3;                // 16B group within 64B quarter-row

    int beg = rowptr[n];
    int end = rowptr[n + 1];
    float di = dinv[n];
    const uint4* xq = (const uint4*)(xwb + (size_t)q * N * 32);  // plane

    float acc[8];
#pragma unroll
    for (int i = 0; i < 8; i++) acc[i] = 0.0f;
    if (p == 0) {
        uint4 w = xq[(size_t)n * 4 + c4];
        acc[0] = di * bfLo(w.x); acc[1] = di * bfHi(w.x);
        acc[2] = di * bfLo(w.y); acc[3] = di * bfHi(w.y);
        acc[4] = di * bfLo(w.z); acc[5] = di * bfHi(w.z);
        acc[6] = di * bfLo(w.w); acc[7] = di * bfHi(w.w);
    }

    for (int base = beg; base < end; base += 64) {
        int cnt = min(64, end - base);
        if (lane < cnt) {
            int s = csr_src[base + lane];
            sS[wbase + lane] = s;
            sD[wbase + lane] = dinv[s];
        }
        // same-wave LDS write->read (lgkmcnt ordered); no barrier needed
#pragma unroll 2
        for (int j = p; j < cnt; j += 16) {
            int sj   = sS[wbase + j];
            float dj = sD[wbase + j];
            uint4 w = xq[(size_t)sj * 4 + c4];
            acc[0] = fmaf(dj, bfLo(w.x), acc[0]);
            acc[1] = fmaf(dj, bfHi(w.x), acc[1]);
            acc[2] = fmaf(dj, bfLo(w.y), acc[2]);
            acc[3] = fmaf(dj, bfHi(w.y), acc[3]);
            acc[4] = fmaf(dj, bfLo(w.z), acc[4]);
            acc[5] = fmaf(dj, bfHi(w.z), acc[5]);
            acc[6] = fmaf(dj, bfLo(w.w), acc[6]);
            acc[7] = fmaf(dj, bfHi(w.w), acc[7]);
        }
    }

#pragma unroll
    for (int i = 0; i < 8; i++) {
        acc[i] += __shfl_xor(acc[i], 4, 64);
        acc[i] += __shfl_xor(acc[i], 8, 64);
        acc[i] += __shfl_xor(acc[i], 16, 64);
        acc[i] += __shfl_xor(acc[i], 32, 64);
    }

    if (p == 0) {
        int colb = q * 32 + c4 * 8;             // global col base (8 cols)
        float4 b0 = *(const float4*)(b + colb);
        float4 b1 = *(const float4*)(b + colb + 4);
        float val[8];
        val[0] = di * acc[0] + b0.x; val[1] = di * acc[1] + b0.y;
        val[2] = di * acc[2] + b0.z; val[3] = di * acc[3] + b0.w;
        val[4] = di * acc[4] + b1.x; val[5] = di * acc[5] + b1.y;
        val[6] = di * acc[6] + b1.z; val[7] = di * acc[7] + b1.w;
        if (mode) {
#pragma unroll
            for (int half = 0; half < 2; half++) {
                float4 mm = *(const float4*)(m + colb + half * 4);
                float4 vv = *(const float4*)(v + colb + half * 4);
                float4 gg = *(const float4*)(g + colb + half * 4);
                float4 be = *(const float4*)(beta + colb + half * 4);
                int o = half * 4;
                val[o+0] = fmaxf((val[o+0] - mm.x) * rsqrtf(vv.x + BN_EPS) * gg.x + be.x, 0.f);
                val[o+1] = fmaxf((val[o+1] - mm.y) * rsqrtf(vv.y + BN_EPS) * gg.y + be.y, 0.f);
                val[o+2] = fmaxf((val[o+2] - mm.z) * rsqrtf(vv.z + BN_EPS) * gg.z + be.z, 0.f);
                val[o+3] = fmaxf((val[o+3] - mm.w) * rsqrtf(vv.w + BN_EPS) * gg.w + be.w, 0.f);
            }
        }
        float4* o4 = (float4*)(out + (size_t)n * HH + colb);
        o4[0] = make_float4(val[0], val[1], val[2], val[3]);
        o4[1] = make_float4(val[4], val[5], val[6], val[7]);
    }
}

// ---------- pool ----------
__global__ __launch_bounds__(128) void k_pool(const float* __restrict__ h,
                                              const int* __restrict__ batch,
                                              float* __restrict__ sums,
                                              float* __restrict__ cnts, int N) {
    int col = threadIdx.x;
    int n0 = blockIdx.x * 128;
    int n1 = min(n0 + 128, N);
    float acc = 0.0f;
    float cnt = 0.0f;
    int curg = batch[n0];
    for (int n = n0; n < n1; n++) {
        int gg = batch[n];
        if (gg != curg) {
            atomAddF(&sums[(size_t)curg * HH + col], acc);
            if (col == 0) atomAddF(&cnts[curg], cnt);
            acc = 0.0f; cnt = 0.0f; curg = gg;
        }
        acc += h[(size_t)n * HH + col];
        cnt += 1.0f;
    }
    atomAddF(&sums[(size_t)curg * HH + col], acc);
    if (col == 0) atomAddF(&cnts[curg], cnt);
}

// ---------- classifier head ----------
__global__ __launch_bounds__(64) void k_cls(const float* __restrict__ sums,
                                            const float* __restrict__ cnts,
                                            const float* __restrict__ Wc1,
                                            const float* __restrict__ bc1,
                                            const float* __restrict__ Wc2,
                                            const float* __restrict__ bc2,
                                            float* __restrict__ out, int Hc, int C) {
    int gI = blockIdx.x;
    int tid = threadIdx.x;
    __shared__ float pooled[HH];
    __shared__ float z[64];
    float cnt = fmaxf(cnts[gI], 1.0f);
    for (int c = tid; c < HH; c += 64) pooled[c] = sums[(size_t)gI * HH + c] / cnt;
    __syncthreads();
    if (tid < Hc) {
        float a = bc1[tid];
        for (int k = 0; k < HH; k++) a += pooled[k] * Wc1[k * Hc + tid];
        z[tid] = fmaxf(a, 0.0f);
    }
    __syncthreads();
    if (tid < C) {
        float a = bc2[tid];
        for (int k = 0; k < Hc; k++) a += z[k] * Wc2[k * C + tid];
        out[(size_t)gI * C + tid] = a;
    }
}

extern "C" void kernel_launch(void* const* d_in, const int* in_sizes, int n_in,
                              void* d_out, int out_size, void* d_ws, size_t ws_size,
                              hipStream_t stream) {
    const float* x     = (const float*)d_in[0];
    const int*   ei    = (const int*)d_in[1];
    const int*   batch = (const int*)d_in[2];
    const float* W1    = (const float*)d_in[3];
    const float* b1    = (const float*)d_in[4];
    const float* W2    = (const float*)d_in[5];
    const float* b2    = (const float*)d_in[6];
    const float* W3    = (const float*)d_in[7];
    const float* b3    = (const float*)d_in[8];
    const float* bn1_g = (const float*)d_in[9];
    const float* bn1_b = (const float*)d_in[10];
    const float* bn1_m = (const float*)d_in[11];
    const float* bn1_v = (const float*)d_in[12];
    const float* bn2_g = (const float*)d_in[13];
    const float* bn2_b = (const float*)d_in[14];
    const float* bn2_m = (const float*)d_in[15];
    const float* bn2_v = (const float*)d_in[16];
    const float* Wc1   = (const float*)d_in[17];
    const float* bc1   = (const float*)d_in[18];
    const float* Wc2   = (const float*)d_in[19];
    const float* bc2   = (const float*)d_in[20];
    float* out = (float*)d_out;

    const int N  = in_sizes[2];
    const int E  = in_sizes[1] / 2;
    const int K0 = in_sizes[0] / N;      // 256
    const int Hc = in_sizes[18];         // 64
    const int C  = in_sizes[20];         // 16
    const int G  = out_size / C;         // 64

    const int* srcv = ei;
    const int* dstv = ei + E;

    // workspace layout
    float* ws = (float*)d_ws;
    size_t NH = (size_t)N * HH;
    size_t Na = (((size_t)N + 255) / 256) * 256;
    size_t Ea = (((size_t)E + 255) / 256) * 256;
    ushort* bufA   = (ushort*)ws;            // 4 planes x N x 32 bf16
    float* bufB    = ws + NH;
    float* dinv    = bufB + NH;
    int*   degInt  = (int*)(dinv + Na);
    int*   rowptr  = degInt + Na;
    int*   csr_src = rowptr + Na + 256;
    uint2* bucketed= (uint2*)(csr_src + Ea);
    int*   gH      = (int*)(bucketed + Ea);
    int*   gC      = gH + 65536;
    int*   totals  = gC + 65536;
    int*   baseArr = totals + 256;
    int*   partials= baseArr + 512;
    float* sums    = (float*)(partials + 256);
    float* cnts    = sums + (size_t)G * HH;
    uint*  Wp1     = (uint*)(cnts + 256);
    uint*  Wp2     = Wp1 + (size_t)K0 * HH;
    uint*  Wp3     = Wp2 + (size_t)HH * HH;

    int tile = (E + 255) / 256;
    int nb   = (int)((N + 255) / 256);
    int gGemm = (N + 63) / 64;
    int ngrps = (N + 3) / 4;
    int gAgg  = 8 * ((ngrps + 1) / 2);       // (node-group, quarter) blocks
    int gPool = (N + 127) / 128;

    // ---- CSR build (no global atomics) ----
    k_ahist<<<256, 256, 0, stream>>>(dstv, gH, E, tile);
    k_scan1<<<256, 256, 0, stream>>>(gH, gC, totals);
    k_scan2<<<1, 256, 0, stream>>>(totals, baseArr);
    k_asc<<<256, 256, 0, stream>>>(srcv, dstv, gC, baseArr, bucketed, E, tile);
    k_bdeg<<<256, 256, 0, stream>>>(bucketed, baseArr, degInt, dinv, N);
    k_scanA<<<nb, 256, 0, stream>>>(degInt, partials, N);
    k_scanB<<<1, 256, 0, stream>>>(partials, nb);
    k_scanC<<<nb, 256, 0, stream>>>(degInt, partials, rowptr, N);
    k_csc<<<256, 256, 0, stream>>>(bucketed, baseArr, rowptr, csr_src, N);

    // ---- weight splits ----
    k_wsplit<<<(128 * (K0 / 2) + 255) / 256, 256, 0, stream>>>(W1, Wp1, K0);
    k_wsplit<<<(128 * (HH / 2) + 255) / 256, 256, 0, stream>>>(W2, Wp2, HH);
    k_wsplit<<<(128 * (HH / 2) + 255) / 256, 256, 0, stream>>>(W3, Wp3, HH);

    // ---- layer 1 ----
    if (K0 == 256)
        k_gemm_mfma<8><<<gGemm, 256, 0, stream>>>(x, Wp1, bufA, N);
    else
        k_gemm_mfma<4><<<gGemm, 256, 0, stream>>>(x, Wp1, bufA, N);
    k_agg<<<gAgg, 256, 0, stream>>>(bufA, dinv, rowptr, csr_src, b1,
                                    bn1_g, bn1_b, bn1_m, bn1_v, bufB, N, 1);
    // ---- layer 2 ----
    k_gemm_mfma<4><<<gGemm, 256, 0, stream>>>(bufB, Wp2, bufA, N);
    k_agg<<<gAgg, 256, 0, stream>>>(bufA, dinv, rowptr, csr_src, b2,
                                    bn2_g, bn2_b, bn2_m, bn2_v, bufB, N, 1);
    // ---- layer 3 ----
    k_gemm_mfma<4><<<gGemm, 256, 0, stream>>>(bufB, Wp3, bufA, N);
    k_agg<<<gAgg, 256, 0, stream>>>(bufA, dinv, rowptr, csr_src, b3,
                                    nullptr, nullptr, nullptr, nullptr, bufB, N, 0);

    // ---- pool + classifier ----
    hipMemsetAsync(sums, 0, ((size_t)G * HH + G) * sizeof(float), stream);
    k_pool<<<gPool, 128, 0, stream>>>(bufB, batch, sums, cnts, N);
    k_cls<<<G, 64, 0, stream>>>(sums, cnts, Wc1, bc1, Wc2, bc2, out, Hc, C);
}

// Round 9
// 385.175 us; speedup vs baseline: 1.4432x; 1.4432x over previous
//
#include <hip/hip_runtime.h>

#define HH 128
#define BN_EPS 1e-5f

typedef __attribute__((ext_vector_type(8))) short short8;
typedef __attribute__((ext_vector_type(4))) float floatx4;

__device__ inline void atomAddF(float* p, float v) { unsafeAtomicAdd(p, v); }

__device__ inline short8 mk8(uint a, uint b, uint c, uint d) {
    union { uint u[4]; short8 s; } t;
    t.u[0] = a; t.u[1] = b; t.u[2] = c; t.u[3] = d;
    return t.s;
}

__device__ inline ushort f2bf(float f) {
    uint u = __float_as_uint(f);
    u = u + 0x7FFFu + ((u >> 16) & 1u);
    return (ushort)(u >> 16);
}

__device__ inline float bfLo(uint u) { return __uint_as_float(u << 16); }
__device__ inline float bfHi(uint u) { return __uint_as_float(u & 0xFFFF0000u); }

__device__ inline void splitPair(float f0, float f1, uint& hw, uint& lw) {
    uint u0 = __float_as_uint(f0), u1 = __float_as_uint(f1);
    hw = __builtin_amdgcn_perm(u1, u0, 0x07060302);
    float r0 = f0 - __uint_as_float(u0 & 0xFFFF0000u);
    float r1 = f1 - __uint_as_float(u1 & 0xFFFF0000u);
    lw = __builtin_amdgcn_perm(__float_as_uint(r1), __float_as_uint(r0), 0x07060302);
}

// ================= CSR build via 2-level bucket sort (NO global atomics) ====

__global__ __launch_bounds__(256) void k_ahist(const int* __restrict__ dst,
                                               int* __restrict__ gH, int E, int tile) {
    __shared__ int hist[256];
    int b = blockIdx.x, tid = threadIdx.x;
    hist[tid] = 0;
    __syncthreads();
    int s0 = b * tile, s1 = min(s0 + tile, E);
    for (int i = s0 + tid; i < s1; i += 256)
        atomicAdd(&hist[((unsigned)dst[i]) >> 8], 1);
    __syncthreads();
    gH[tid * 256 + b] = hist[tid];
}

__global__ __launch_bounds__(256) void k_scan1(const int* __restrict__ gH,
                                               int* __restrict__ gC,
                                               int* __restrict__ totals) {
    __shared__ int s[256];
    int h = blockIdx.x, b = threadIdx.x;
    int v = gH[h * 256 + b];
    s[b] = v;
    __syncthreads();
    for (int off = 1; off < 256; off <<= 1) {
        int t = (b >= off) ? s[b - off] : 0;
        __syncthreads();
        s[b] += t;
        __syncthreads();
    }
    gC[h * 256 + b] = s[b] - v;
    if (b == 255) totals[h] = s[255];
}

__global__ __launch_bounds__(256) void k_scan2(const int* __restrict__ totals,
                                               int* __restrict__ base) {
    __shared__ int s[256];
    int tid = threadIdx.x;
    int v = totals[tid];
    s[tid] = v;
    __syncthreads();
    for (int off = 1; off < 256; off <<= 1) {
        int t = (tid >= off) ? s[tid - off] : 0;
        __syncthreads();
        s[tid] += t;
        __syncthreads();
    }
    base[tid] = s[tid] - v;
    if (tid == 255) base[256] = s[255];
}

__global__ __launch_bounds__(256) void k_asc(const int* __restrict__ src,
                                             const int* __restrict__ dst,
                                             const int* __restrict__ gC,
                                             const int* __restrict__ base,
                                             uint2* __restrict__ bucketed,
                                             int E, int tile) {
    __shared__ int cur[256];
    int b = blockIdx.x, tid = threadIdx.x;
    cur[tid] = gC[tid * 256 + b] + base[tid];
    __syncthreads();
    int s0 = b * tile, s1 = min(s0 + tile, E);
    for (int i = s0 + tid; i < s1; i += 256) {
        int d = dst[i];
        int pos = atomicAdd(&cur[((unsigned)d) >> 8], 1);
        bucketed[pos] = make_uint2((uint)src[i], (uint)d);
    }
}

__global__ __launch_bounds__(256) void k_bdeg(const uint2* __restrict__ bucketed,
                                              const int* __restrict__ base,
                                              int* __restrict__ degInt,
                                              float* __restrict__ dinv, int N) {
    __shared__ int hist[256];
    int h = blockIdx.x, tid = threadIdx.x;
    hist[tid] = 0;
    __syncthreads();
    int s0 = base[h], s1 = base[h + 1];
    for (int i = s0 + tid; i < s1; i += 256)
        atomicAdd(&hist[bucketed[i].y & 255u], 1);
    __syncthreads();
    int n = h * 256 + tid;
    if (n < N) {
        int d = hist[tid];
        degInt[n] = d;
        dinv[n] = rsqrtf((float)d + 1.0f);
    }
}

__global__ __launch_bounds__(256) void k_scanA(const int* __restrict__ degInt,
                                               int* __restrict__ partials, int N) {
    __shared__ int s[256];
    int i = blockIdx.x * 256 + threadIdx.x;
    int d = (i < N) ? degInt[i] : 0;
    s[threadIdx.x] = d;
    __syncthreads();
    for (int off = 128; off > 0; off >>= 1) {
        if (threadIdx.x < off) s[threadIdx.x] += s[threadIdx.x + off];
        __syncthreads();
    }
    if (threadIdx.x == 0) partials[blockIdx.x] = s[0];
}

__global__ __launch_bounds__(256) void k_scanB(int* __restrict__ partials, int nb) {
    __shared__ int s[256];
    int tid = threadIdx.x;
    int v = (tid < nb) ? partials[tid] : 0;
    s[tid] = v;
    __syncthreads();
    for (int off = 1; off < 256; off <<= 1) {
        int t = (tid >= off) ? s[tid - off] : 0;
        __syncthreads();
        s[tid] += t;
        __syncthreads();
    }
    partials[tid] = s[tid] - v;
}

__global__ __launch_bounds__(256) void k_scanC(const int* __restrict__ degInt,
                                               const int* __restrict__ partials,
                                               int* __restrict__ rowptr, int N) {
    __shared__ int s[256];
    int tid = threadIdx.x;
    int i = blockIdx.x * 256 + tid;
    int d = (i < N) ? degInt[i] : 0;
    s[tid] = d;
    __syncthreads();
    for (int off = 1; off < 256; off <<= 1) {
        int t = (tid >= off) ? s[tid - off] : 0;
        __syncthreads();
        s[tid] += t;
        __syncthreads();
    }
    int incl = s[tid];
    int b = partials[blockIdx.x];
    if (i < N) {
        rowptr[i] = b + incl - d;
        if (i == N - 1) rowptr[N] = b + incl;
    }
}

// pass C: scatter (src, dinv[src]) pairs into CSR order (LDS cursors)
__global__ __launch_bounds__(256) void k_csc(const uint2* __restrict__ bucketed,
                                             const int* __restrict__ base,
                                             const int* __restrict__ rowptr,
                                             const float* __restrict__ dinv,
                                             uint2* __restrict__ edata, int N) {
    __shared__ int cur[256];
    int h = blockIdx.x, tid = threadIdx.x;
    int n = h * 256 + tid;
    cur[tid] = (n < N) ? rowptr[n] : 0;
    __syncthreads();
    int s0 = base[h], s1 = base[h + 1];
    for (int i = s0 + tid; i < s1; i += 256) {
        uint2 e = bucketed[i];
        int pos = atomicAdd(&cur[e.y & 255u], 1);
        edata[pos] = make_uint2(e.x, __float_as_uint(dinv[e.x]));
    }
}

// ---------- W split ----------
__global__ void k_wsplit(const float* __restrict__ W, uint* __restrict__ Wp, int K) {
    int t = blockIdx.x * 256 + threadIdx.x;
    int half = K >> 1;
    if (t >= 128 * half) return;
    int n = t / half;
    int p = t - n * half;
    uint hw, lw;
    splitPair(W[(2 * p) * HH + n], W[(2 * p + 1) * HH + n], hw, lw);
    Wp[n * K + 2 * p]     = hw;
    Wp[n * K + 2 * p + 1] = lw;
}

// ---------- MFMA GEMM: A[N,K] fp32 @ W[K,128] -> out[N,128] bf16 ----------
template<int KT>   // K = KT*32
__global__ __launch_bounds__(256) void k_gemm_mfma(const float* __restrict__ A,
                                                   const uint* __restrict__ Wp,
                                                   ushort* __restrict__ out,
                                                   int N) {
    const int K = KT * 32;
    const int NCH = KT / 2;
    __shared__ uint Bs[128 * 68];
    int tid  = threadIdx.x;
    int wave = tid >> 6;
    int lane = tid & 63;
    int m16  = lane & 15;
    int quad = lane >> 4;
    int row  = blockIdx.x * 64 + wave * 16 + m16;
    int rowc = min(row, N - 1);

    const float4* a4 = (const float4*)(A + (size_t)rowc * K);
    float4 araw[2 * KT];
#pragma unroll
    for (int kt = 0; kt < KT; kt++) {
        araw[2 * kt]     = a4[kt * 8 + quad * 2];
        araw[2 * kt + 1] = a4[kt * 8 + quad * 2 + 1];
    }

    floatx4 acc[8];
#pragma unroll
    for (int c = 0; c < 8; c++) acc[c] = (floatx4){0.f, 0.f, 0.f, 0.f};

    int sn0 = tid >> 4;
    int sq4 = tid & 15;

    for (int ch = 0; ch < NCH; ch++) {
#pragma unroll
        for (int i = 0; i < 8; i++) {
            int n = i * 16 + sn0;
            *(uint4*)&Bs[n * 68 + sq4 * 4] =
                *(const uint4*)&Wp[(size_t)n * K + ch * 64 + sq4 * 4];
        }
        __syncthreads();

#pragma unroll
        for (int ktl = 0; ktl < 2; ktl++) {
            int ktg = ch * 2 + ktl;
            float4 f0 = araw[2 * ktg];
            float4 f1 = araw[2 * ktg + 1];
            uint ahw[4], alw[4];
            splitPair(f0.x, f0.y, ahw[0], alw[0]);
            splitPair(f0.z, f0.w, ahw[1], alw[1]);
            splitPair(f1.x, f1.y, ahw[2], alw[2]);
            splitPair(f1.z, f1.w, ahw[3], alw[3]);
            short8 a_hi = mk8(ahw[0], ahw[1], ahw[2], ahw[3]);
            short8 a_lo = mk8(alw[0], alw[1], alw[2], alw[3]);

#pragma unroll
            for (int c = 0; c < 8; c++) {
                const uint* bp = &Bs[(c * 16 + m16) * 68 + ktl * 32 + quad * 8];
                uint4 w0 = *(const uint4*)bp;
                uint4 w1 = *(const uint4*)(bp + 4);
                short8 b_hi = mk8(w0.x, w0.z, w1.x, w1.z);
                short8 b_lo = mk8(w0.y, w0.w, w1.y, w1.w);
                acc[c] = __builtin_amdgcn_mfma_f32_16x16x32_bf16(a_hi, b_hi, acc[c], 0, 0, 0);
                acc[c] = __builtin_amdgcn_mfma_f32_16x16x32_bf16(a_lo, b_hi, acc[c], 0, 0, 0);
                acc[c] = __builtin_amdgcn_mfma_f32_16x16x32_bf16(a_hi, b_lo, acc[c], 0, 0, 0);
            }
        }
        __syncthreads();
    }

    int rowbase = blockIdx.x * 64 + wave * 16 + quad * 4;
#pragma unroll
    for (int c = 0; c < 8; c++) {
#pragma unroll
        for (int r = 0; r < 4; r++) {
            int rr = rowbase + r;
            if (rr < N) out[(size_t)rr * HH + c * 16 + m16] = f2bf(acc[c][r]);
        }
    }
}

// ---------- CSR aggregation (bf16 gather, quarter-wave phases) ----------
// wave-per-node; lane = q*16+c16: phase q handles edges j%4==q, lane covers
// 8 cols (16B). Edge data (src,dinv) precomputed -> single coalesced stage.
__global__ __launch_bounds__(256) void k_agg(const ushort* __restrict__ xwb,
                                             const float* __restrict__ dinv,
                                             const int* __restrict__ rowptr,
                                             const uint2* __restrict__ edata,
                                             const float* __restrict__ b,
                                             const float* __restrict__ g,
                                             const float* __restrict__ beta,
                                             const float* __restrict__ m,
                                             const float* __restrict__ v,
                                             float* __restrict__ out,
                                             int N, int mode) {
    __shared__ uint  sS[256];
    __shared__ float sD[256];
    int wave = threadIdx.x >> 6;
    int lane = threadIdx.x & 63;
    int n = blockIdx.x * 4 + wave;
    if (n >= N) return;
    int wbase = wave * 64;
    int q   = lane >> 4;      // edge phase 0..3
    int c16 = lane & 15;      // 16B col group (8 bf16 cols)

    int beg = rowptr[n];
    int end = rowptr[n + 1];
    float di = dinv[n];
    const char* xb = (const char*)xwb;
    uint coff = (uint)c16 << 4;      // byte offset within row (row = 256B)

    float acc[8];
#pragma unroll
    for (int i = 0; i < 8; i++) acc[i] = 0.0f;
    if (q == 0) {
        uint4 w = *(const uint4*)(xb + (((uint)n << 8) | coff));
        acc[0] = di * bfLo(w.x); acc[1] = di * bfHi(w.x);
        acc[2] = di * bfLo(w.y); acc[3] = di * bfHi(w.y);
        acc[4] = di * bfLo(w.z); acc[5] = di * bfHi(w.z);
        acc[6] = di * bfLo(w.w); acc[7] = di * bfHi(w.w);
    }

    for (int base = beg; base < end; base += 64) {
        int cnt = min(64, end - base);
        if (lane < cnt) {
            uint2 e = edata[base + lane];
            sS[wbase + lane] = e.x << 8;          // precomputed byte offset
            sD[wbase + lane] = __uint_as_float(e.y);
        }
        // same-wave LDS write->read (lgkmcnt ordered); no barrier needed
#pragma unroll 4
        for (int j = q; j < cnt; j += 4) {
            uint so   = sS[wbase + j];
            float dj  = sD[wbase + j];
            uint4 w = *(const uint4*)(xb + (so | coff));
            acc[0] = fmaf(dj, bfLo(w.x), acc[0]);
            acc[1] = fmaf(dj, bfHi(w.x), acc[1]);
            acc[2] = fmaf(dj, bfLo(w.y), acc[2]);
            acc[3] = fmaf(dj, bfHi(w.y), acc[3]);
            acc[4] = fmaf(dj, bfLo(w.z), acc[4]);
            acc[5] = fmaf(dj, bfHi(w.z), acc[5]);
            acc[6] = fmaf(dj, bfLo(w.w), acc[6]);
            acc[7] = fmaf(dj, bfHi(w.w), acc[7]);
        }
    }

#pragma unroll
    for (int i = 0; i < 8; i++) {
        acc[i] += __shfl_xor(acc[i], 16, 64);
        acc[i] += __shfl_xor(acc[i], 32, 64);
    }

    if (q == 0) {
        float4 b0 = ((const float4*)b)[c16 * 2];
        float4 b1 = ((const float4*)b)[c16 * 2 + 1];
        float val[8];
        val[0] = di * acc[0] + b0.x; val[1] = di * acc[1] + b0.y;
        val[2] = di * acc[2] + b0.z; val[3] = di * acc[3] + b0.w;
        val[4] = di * acc[4] + b1.x; val[5] = di * acc[5] + b1.y;
        val[6] = di * acc[6] + b1.z; val[7] = di * acc[7] + b1.w;
        if (mode) {
#pragma unroll
            for (int half = 0; half < 2; half++) {
                float4 mm = ((const float4*)m)[c16 * 2 + half];
                float4 vv = ((const float4*)v)[c16 * 2 + half];
                float4 gg = ((const float4*)g)[c16 * 2 + half];
                float4 be = ((const float4*)beta)[c16 * 2 + half];
                int o = half * 4;
                val[o+0] = fmaxf((val[o+0] - mm.x) * rsqrtf(vv.x + BN_EPS) * gg.x + be.x, 0.f);
                val[o+1] = fmaxf((val[o+1] - mm.y) * rsqrtf(vv.y + BN_EPS) * gg.y + be.y, 0.f);
                val[o+2] = fmaxf((val[o+2] - mm.z) * rsqrtf(vv.z + BN_EPS) * gg.z + be.z, 0.f);
                val[o+3] = fmaxf((val[o+3] - mm.w) * rsqrtf(vv.w + BN_EPS) * gg.w + be.w, 0.f);
            }
        }
        float4* o4 = (float4*)(out + (size_t)n * HH + c16 * 8);
        o4[0] = make_float4(val[0], val[1], val[2], val[3]);
        o4[1] = make_float4(val[4], val[5], val[6], val[7]);
    }
}

// ---------- pool ----------
__global__ __launch_bounds__(128) void k_pool(const float* __restrict__ h,
                                              const int* __restrict__ batch,
                                              float* __restrict__ sums,
                                              float* __restrict__ cnts, int N) {
    int col = threadIdx.x;
    int n0 = blockIdx.x * 128;
    int n1 = min(n0 + 128, N);
    float acc = 0.0f;
    float cnt = 0.0f;
    int curg = batch[n0];
    for (int n = n0; n < n1; n++) {
        int gg = batch[n];
        if (gg != curg) {
            atomAddF(&sums[(size_t)curg * HH + col], acc);
            if (col == 0) atomAddF(&cnts[curg], cnt);
            acc = 0.0f; cnt = 0.0f; curg = gg;
        }
        acc += h[(size_t)n * HH + col];
        cnt += 1.0f;
    }
    atomAddF(&sums[(size_t)curg * HH + col], acc);
    if (col == 0) atomAddF(&cnts[curg], cnt);
}

// ---------- classifier head ----------
__global__ __launch_bounds__(64) void k_cls(const float* __restrict__ sums,
                                            const float* __restrict__ cnts,
                                            const float* __restrict__ Wc1,
                                            const float* __restrict__ bc1,
                                            const float* __restrict__ Wc2,
                                            const float* __restrict__ bc2,
                                            float* __restrict__ out, int Hc, int C) {
    int gI = blockIdx.x;
    int tid = threadIdx.x;
    __shared__ float pooled[HH];
    __shared__ float z[64];
    float cnt = fmaxf(cnts[gI], 1.0f);
    for (int c = tid; c < HH; c += 64) pooled[c] = sums[(size_t)gI * HH + c] / cnt;
    __syncthreads();
    if (tid < Hc) {
        float a = bc1[tid];
        for (int k = 0; k < HH; k++) a += pooled[k] * Wc1[k * Hc + tid];
        z[tid] = fmaxf(a, 0.0f);
    }
    __syncthreads();
    if (tid < C) {
        float a = bc2[tid];
        for (int k = 0; k < Hc; k++) a += z[k] * Wc2[k * C + tid];
        out[(size_t)gI * C + tid] = a;
    }
}

extern "C" void kernel_launch(void* const* d_in, const int* in_sizes, int n_in,
                              void* d_out, int out_size, void* d_ws, size_t ws_size,
                              hipStream_t stream) {
    const float* x     = (const float*)d_in[0];
    const int*   ei    = (const int*)d_in[1];
    const int*   batch = (const int*)d_in[2];
    const float* W1    = (const float*)d_in[3];
    const float* b1    = (const float*)d_in[4];
    const float* W2    = (const float*)d_in[5];
    const float* b2    = (const float*)d_in[6];
    const float* W3    = (const float*)d_in[7];
    const float* b3    = (const float*)d_in[8];
    const float* bn1_g = (const float*)d_in[9];
    const float* bn1_b = (const float*)d_in[10];
    const float* bn1_m = (const float*)d_in[11];
    const float* bn1_v = (const float*)d_in[12];
    const float* bn2_g = (const float*)d_in[13];
    const float* bn2_b = (const float*)d_in[14];
    const float* bn2_m = (const float*)d_in[15];
    const float* bn2_v = (const float*)d_in[16];
    const float* Wc1   = (const float*)d_in[17];
    const float* bc1   = (const float*)d_in[18];
    const float* Wc2   = (const float*)d_in[19];
    const float* bc2   = (const float*)d_in[20];
    float* out = (float*)d_out;

    const int N  = in_sizes[2];
    const int E  = in_sizes[1] / 2;
    const int K0 = in_sizes[0] / N;      // 256
    const int Hc = in_sizes[18];         // 64
    const int C  = in_sizes[20];         // 16
    const int G  = out_size / C;         // 64

    const int* srcv = ei;
    const int* dstv = ei + E;

    // workspace layout
    float* ws = (float*)d_ws;
    size_t NH = (size_t)N * HH;
    size_t Na = (((size_t)N + 255) / 256) * 256;
    size_t Ea = (((size_t)E + 255) / 256) * 256;
    ushort* bufA   = (ushort*)ws;            // N*128 bf16
    float* bufB    = ws + NH;
    float* dinv    = bufB + NH;
    int*   degInt  = (int*)(dinv + Na);
    int*   rowptr  = degInt + Na;
    uint2* edata   = (uint2*)(rowptr + Na + 256);  // E * 8B
    uint2* bucketed= edata + Ea;                   // E * 8B
    int*   gH      = (int*)(bucketed + Ea);
    int*   gC      = gH + 65536;
    int*   totals  = gC + 65536;
    int*   baseArr = totals + 256;
    int*   partials= baseArr + 512;
    float* sums    = (float*)(partials + 256);
    float* cnts    = sums + (size_t)G * HH;
    uint*  Wp1     = (uint*)(cnts + 256);
    uint*  Wp2     = Wp1 + (size_t)K0 * HH;
    uint*  Wp3     = Wp2 + (size_t)HH * HH;

    int tile = (E + 255) / 256;
    int nb   = (int)((N + 255) / 256);
    int gGemm = (N + 63) / 64;
    int gAgg  = (N + 3) / 4;
    int gPool = (N + 127) / 128;

    // ---- CSR build (no global atomics) ----
    k_ahist<<<256, 256, 0, stream>>>(dstv, gH, E, tile);
    k_scan1<<<256, 256, 0, stream>>>(gH, gC, totals);
    k_scan2<<<1, 256, 0, stream>>>(totals, baseArr);
    k_asc<<<256, 256, 0, stream>>>(srcv, dstv, gC, baseArr, bucketed, E, tile);
    k_bdeg<<<256, 256, 0, stream>>>(bucketed, baseArr, degInt, dinv, N);
    k_scanA<<<nb, 256, 0, stream>>>(degInt, partials, N);
    k_scanB<<<1, 256, 0, stream>>>(partials, nb);
    k_scanC<<<nb, 256, 0, stream>>>(degInt, partials, rowptr, N);
    k_csc<<<256, 256, 0, stream>>>(bucketed, baseArr, rowptr, dinv, edata, N);

    // ---- weight splits ----
    k_wsplit<<<(128 * (K0 / 2) + 255) / 256, 256, 0, stream>>>(W1, Wp1, K0);
    k_wsplit<<<(128 * (HH / 2) + 255) / 256, 256, 0, stream>>>(W2, Wp2, HH);
    k_wsplit<<<(128 * (HH / 2) + 255) / 256, 256, 0, stream>>>(W3, Wp3, HH);

    // ---- layer 1 ----
    if (K0 == 256)
        k_gemm_mfma<8><<<gGemm, 256, 0, stream>>>(x, Wp1, bufA, N);
    else
        k_gemm_mfma<4><<<gGemm, 256, 0, stream>>>(x, Wp1, bufA, N);
    k_agg<<<gAgg, 256, 0, stream>>>(bufA, dinv, rowptr, edata, b1,
                                    bn1_g, bn1_b, bn1_m, bn1_v, bufB, N, 1);
    // ---- layer 2 ----
    k_gemm_mfma<4><<<gGemm, 256, 0, stream>>>(bufB, Wp2, bufA, N);
    k_agg<<<gAgg, 256, 0, stream>>>(bufA, dinv, rowptr, edata, b2,
                                    bn2_g, bn2_b, bn2_m, bn2_v, bufB, N, 1);
    // ---- layer 3 ----
    k_gemm_mfma<4><<<gGemm, 256, 0, stream>>>(bufB, Wp3, bufA, N);
    k_agg<<<gAgg, 256, 0, stream>>>(bufA, dinv, rowptr, edata, b3,
                                    nullptr, nullptr, nullptr, nullptr, bufB, N, 0);

    // ---- pool + classifier ----
    hipMemsetAsync(sums, 0, ((size_t)G * HH + G) * sizeof(float), stream);
    k_pool<<<gPool, 128, 0, stream>>>(bufB, batch, sums, cnts, N);
    k_cls<<<G, 64, 0, stream>>>(sums, cnts, Wc1, bc1, Wc2, bc2, out, Hc, C);
}

// Round 10
// 362.534 us; speedup vs baseline: 1.5333x; 1.0625x over previous
//
#include <hip/hip_runtime.h>

#define HH 128
#define BN_EPS 1e-5f

typedef __attribute__((ext_vector_type(8))) short short8;
typedef __attribute__((ext_vector_type(4))) float floatx4;

__device__ inline void atomAddF(float* p, float v) { unsafeAtomicAdd(p, v); }

__device__ inline short8 mk8(uint a, uint b, uint c, uint d) {
    union { uint u[4]; short8 s; } t;
    t.u[0] = a; t.u[1] = b; t.u[2] = c; t.u[3] = d;
    return t.s;
}

__device__ inline ushort f2bf(float f) {
    uint u = __float_as_uint(f);
    u = u + 0x7FFFu + ((u >> 16) & 1u);
    return (ushort)(u >> 16);
}

__device__ inline uint packbf(float lo, float hi) {
    return ((uint)f2bf(hi) << 16) | (uint)f2bf(lo);
}

__device__ inline float bfLo(uint u) { return __uint_as_float(u << 16); }
__device__ inline float bfHi(uint u) { return __uint_as_float(u & 0xFFFF0000u); }

__device__ inline void splitPair(float f0, float f1, uint& hw, uint& lw) {
    uint u0 = __float_as_uint(f0), u1 = __float_as_uint(f1);
    hw = __builtin_amdgcn_perm(u1, u0, 0x07060302);
    float r0 = f0 - __uint_as_float(u0 & 0xFFFF0000u);
    float r1 = f1 - __uint_as_float(u1 & 0xFFFF0000u);
    lw = __builtin_amdgcn_perm(__float_as_uint(r1), __float_as_uint(r0), 0x07060302);
}

// ================= CSR build via 2-level bucket sort (NO global atomics) ====

__global__ __launch_bounds__(256) void k_ahist(const int* __restrict__ dst,
                                               int* __restrict__ gH, int E, int tile) {
    __shared__ int hist[256];
    int b = blockIdx.x, tid = threadIdx.x;
    hist[tid] = 0;
    __syncthreads();
    int s0 = b * tile, s1 = min(s0 + tile, E);
    for (int i = s0 + tid; i < s1; i += 256)
        atomicAdd(&hist[((unsigned)dst[i]) >> 8], 1);
    __syncthreads();
    gH[tid * 256 + b] = hist[tid];
}

__global__ __launch_bounds__(256) void k_scan1(const int* __restrict__ gH,
                                               int* __restrict__ gC,
                                               int* __restrict__ totals) {
    __shared__ int s[256];
    int h = blockIdx.x, b = threadIdx.x;
    int v = gH[h * 256 + b];
    s[b] = v;
    __syncthreads();
    for (int off = 1; off < 256; off <<= 1) {
        int t = (b >= off) ? s[b - off] : 0;
        __syncthreads();
        s[b] += t;
        __syncthreads();
    }
    gC[h * 256 + b] = s[b] - v;
    if (b == 255) totals[h] = s[255];
}

__global__ __launch_bounds__(256) void k_scan2(const int* __restrict__ totals,
                                               int* __restrict__ base) {
    __shared__ int s[256];
    int tid = threadIdx.x;
    int v = totals[tid];
    s[tid] = v;
    __syncthreads();
    for (int off = 1; off < 256; off <<= 1) {
        int t = (tid >= off) ? s[tid - off] : 0;
        __syncthreads();
        s[tid] += t;
        __syncthreads();
    }
    base[tid] = s[tid] - v;
    if (tid == 255) base[256] = s[255];
}

__global__ __launch_bounds__(256) void k_asc(const int* __restrict__ src,
                                             const int* __restrict__ dst,
                                             const int* __restrict__ gC,
                                             const int* __restrict__ base,
                                             uint2* __restrict__ bucketed,
                                             int E, int tile) {
    __shared__ int cur[256];
    int b = blockIdx.x, tid = threadIdx.x;
    cur[tid] = gC[tid * 256 + b] + base[tid];
    __syncthreads();
    int s0 = b * tile, s1 = min(s0 + tile, E);
    for (int i = s0 + tid; i < s1; i += 256) {
        int d = dst[i];
        int pos = atomicAdd(&cur[((unsigned)d) >> 8], 1);
        bucketed[pos] = make_uint2((uint)src[i], (uint)d);
    }
}

__global__ __launch_bounds__(256) void k_bdeg(const uint2* __restrict__ bucketed,
                                              const int* __restrict__ base,
                                              int* __restrict__ degInt,
                                              float* __restrict__ dinv, int N) {
    __shared__ int hist[256];
    int h = blockIdx.x, tid = threadIdx.x;
    hist[tid] = 0;
    __syncthreads();
    int s0 = base[h], s1 = base[h + 1];
    for (int i = s0 + tid; i < s1; i += 256)
        atomicAdd(&hist[bucketed[i].y & 255u], 1);
    __syncthreads();
    int n = h * 256 + tid;
    if (n < N) {
        int d = hist[tid];
        degInt[n] = d;
        dinv[n] = rsqrtf((float)d + 1.0f);
    }
}

__global__ __launch_bounds__(256) void k_scanA(const int* __restrict__ degInt,
                                               int* __restrict__ partials, int N) {
    __shared__ int s[256];
    int i = blockIdx.x * 256 + threadIdx.x;
    int d = (i < N) ? degInt[i] : 0;
    s[threadIdx.x] = d;
    __syncthreads();
    for (int off = 128; off > 0; off >>= 1) {
        if (threadIdx.x < off) s[threadIdx.x] += s[threadIdx.x + off];
        __syncthreads();
    }
    if (threadIdx.x == 0) partials[blockIdx.x] = s[0];
}

__global__ __launch_bounds__(256) void k_scanB(int* __restrict__ partials, int nb) {
    __shared__ int s[256];
    int tid = threadIdx.x;
    int v = (tid < nb) ? partials[tid] : 0;
    s[tid] = v;
    __syncthreads();
    for (int off = 1; off < 256; off <<= 1) {
        int t = (tid >= off) ? s[tid - off] : 0;
        __syncthreads();
        s[tid] += t;
        __syncthreads();
    }
    partials[tid] = s[tid] - v;
}

__global__ __launch_bounds__(256) void k_scanC(const int* __restrict__ degInt,
                                               const int* __restrict__ partials,
                                               int* __restrict__ rowptr, int N) {
    __shared__ int s[256];
    int tid = threadIdx.x;
    int i = blockIdx.x * 256 + tid;
    int d = (i < N) ? degInt[i] : 0;
    s[tid] = d;
    __syncthreads();
    for (int off = 1; off < 256; off <<= 1) {
        int t = (tid >= off) ? s[tid - off] : 0;
        __syncthreads();
        s[tid] += t;
        __syncthreads();
    }
    int incl = s[tid];
    int b = partials[blockIdx.x];
    if (i < N) {
        rowptr[i] = b + incl - d;
        if (i == N - 1) rowptr[N] = b + incl;
    }
}

// pass C: scatter (src, dinv[src]) pairs into CSR order (LDS cursors)
__global__ __launch_bounds__(256) void k_csc(const uint2* __restrict__ bucketed,
                                             const int* __restrict__ base,
                                             const int* __restrict__ rowptr,
                                             const float* __restrict__ dinv,
                                             uint2* __restrict__ edata, int N) {
    __shared__ int cur[256];
    int h = blockIdx.x, tid = threadIdx.x;
    int n = h * 256 + tid;
    cur[tid] = (n < N) ? rowptr[n] : 0;
    __syncthreads();
    int s0 = base[h], s1 = base[h + 1];
    for (int i = s0 + tid; i < s1; i += 256) {
        uint2 e = bucketed[i];
        int pos = atomicAdd(&cur[e.y & 255u], 1);
        edata[pos] = make_uint2(e.x, __float_as_uint(dinv[e.x]));
    }
}

// ---------- W split ----------
__global__ void k_wsplit(const float* __restrict__ W, uint* __restrict__ Wp, int K) {
    int t = blockIdx.x * 256 + threadIdx.x;
    int half = K >> 1;
    if (t >= 128 * half) return;
    int n = t / half;
    int p = t - n * half;
    uint hw, lw;
    splitPair(W[(2 * p) * HH + n], W[(2 * p + 1) * HH + n], hw, lw);
    Wp[n * K + 2 * p]     = hw;
    Wp[n * K + 2 * p + 1] = lw;
}

// ---------- MFMA GEMM (fp32 A, 3-term split): layer 1 ----------
template<int KT>   // K = KT*32
__global__ __launch_bounds__(256) void k_gemm_mfma(const float* __restrict__ A,
                                                   const uint* __restrict__ Wp,
                                                   ushort* __restrict__ out,
                                                   int N) {
    const int K = KT * 32;
    const int NCH = KT / 2;
    __shared__ uint Bs[128 * 68];
    int tid  = threadIdx.x;
    int wave = tid >> 6;
    int lane = tid & 63;
    int m16  = lane & 15;
    int quad = lane >> 4;
    int row  = blockIdx.x * 64 + wave * 16 + m16;
    int rowc = min(row, N - 1);

    const float4* a4 = (const float4*)(A + (size_t)rowc * K);
    float4 araw[2 * KT];
#pragma unroll
    for (int kt = 0; kt < KT; kt++) {
        araw[2 * kt]     = a4[kt * 8 + quad * 2];
        araw[2 * kt + 1] = a4[kt * 8 + quad * 2 + 1];
    }

    floatx4 acc[8];
#pragma unroll
    for (int c = 0; c < 8; c++) acc[c] = (floatx4){0.f, 0.f, 0.f, 0.f};

    int sn0 = tid >> 4;
    int sq4 = tid & 15;

    for (int ch = 0; ch < NCH; ch++) {
#pragma unroll
        for (int i = 0; i < 8; i++) {
            int n = i * 16 + sn0;
            *(uint4*)&Bs[n * 68 + sq4 * 4] =
                *(const uint4*)&Wp[(size_t)n * K + ch * 64 + sq4 * 4];
        }
        __syncthreads();

#pragma unroll
        for (int ktl = 0; ktl < 2; ktl++) {
            int ktg = ch * 2 + ktl;
            float4 f0 = araw[2 * ktg];
            float4 f1 = araw[2 * ktg + 1];
            uint ahw[4], alw[4];
            splitPair(f0.x, f0.y, ahw[0], alw[0]);
            splitPair(f0.z, f0.w, ahw[1], alw[1]);
            splitPair(f1.x, f1.y, ahw[2], alw[2]);
            splitPair(f1.z, f1.w, ahw[3], alw[3]);
            short8 a_hi = mk8(ahw[0], ahw[1], ahw[2], ahw[3]);
            short8 a_lo = mk8(alw[0], alw[1], alw[2], alw[3]);

#pragma unroll
            for (int c = 0; c < 8; c++) {
                const uint* bp = &Bs[(c * 16 + m16) * 68 + ktl * 32 + quad * 8];
                uint4 w0 = *(const uint4*)bp;
                uint4 w1 = *(const uint4*)(bp + 4);
                short8 b_hi = mk8(w0.x, w0.z, w1.x, w1.z);
                short8 b_lo = mk8(w0.y, w0.w, w1.y, w1.w);
                acc[c] = __builtin_amdgcn_mfma_f32_16x16x32_bf16(a_hi, b_hi, acc[c], 0, 0, 0);
                acc[c] = __builtin_amdgcn_mfma_f32_16x16x32_bf16(a_lo, b_hi, acc[c], 0, 0, 0);
                acc[c] = __builtin_amdgcn_mfma_f32_16x16x32_bf16(a_hi, b_lo, acc[c], 0, 0, 0);
            }
        }
        __syncthreads();
    }

    int rowbase = blockIdx.x * 64 + wave * 16 + quad * 4;
#pragma unroll
    for (int c = 0; c < 8; c++) {
#pragma unroll
        for (int r = 0; r < 4; r++) {
            int rr = rowbase + r;
            if (rr < N) out[(size_t)rr * HH + c * 16 + m16] = f2bf(acc[c][r]);
        }
    }
}

// ---------- MFMA GEMM (bf16 A, 2-term W-split): layers 2,3 ----------
template<int KT>   // K = KT*32, A is bf16 row-major [N][K]
__global__ __launch_bounds__(256) void k_gemm_bf(const ushort* __restrict__ A,
                                                 const uint* __restrict__ Wp,
                                                 ushort* __restrict__ out,
                                                 int N) {
    const int K = KT * 32;
    const int NCH = KT / 2;
    __shared__ uint Bs[128 * 68];
    int tid  = threadIdx.x;
    int wave = tid >> 6;
    int lane = tid & 63;
    int m16  = lane & 15;
    int quad = lane >> 4;
    int row  = blockIdx.x * 64 + wave * 16 + m16;
    int rowc = min(row, N - 1);

    const uint4* a4 = (const uint4*)(A + (size_t)rowc * K);   // 8 bf16 per uint4
    uint4 araw[KT];
#pragma unroll
    for (int kt = 0; kt < KT; kt++) araw[kt] = a4[kt * 4 + quad];

    floatx4 acc[8];
#pragma unroll
    for (int c = 0; c < 8; c++) acc[c] = (floatx4){0.f, 0.f, 0.f, 0.f};

    int sn0 = tid >> 4;
    int sq4 = tid & 15;

    for (int ch = 0; ch < NCH; ch++) {
#pragma unroll
        for (int i = 0; i < 8; i++) {
            int n = i * 16 + sn0;
            *(uint4*)&Bs[n * 68 + sq4 * 4] =
                *(const uint4*)&Wp[(size_t)n * K + ch * 64 + sq4 * 4];
        }
        __syncthreads();

#pragma unroll
        for (int ktl = 0; ktl < 2; ktl++) {
            uint4 av = araw[ch * 2 + ktl];
            short8 a = mk8(av.x, av.y, av.z, av.w);
#pragma unroll
            for (int c = 0; c < 8; c++) {
                const uint* bp = &Bs[(c * 16 + m16) * 68 + ktl * 32 + quad * 8];
                uint4 w0 = *(const uint4*)bp;
                uint4 w1 = *(const uint4*)(bp + 4);
                short8 b_hi = mk8(w0.x, w0.z, w1.x, w1.z);
                short8 b_lo = mk8(w0.y, w0.w, w1.y, w1.w);
                acc[c] = __builtin_amdgcn_mfma_f32_16x16x32_bf16(a, b_hi, acc[c], 0, 0, 0);
                acc[c] = __builtin_amdgcn_mfma_f32_16x16x32_bf16(a, b_lo, acc[c], 0, 0, 0);
            }
        }
        __syncthreads();
    }

    int rowbase = blockIdx.x * 64 + wave * 16 + quad * 4;
#pragma unroll
    for (int c = 0; c < 8; c++) {
#pragma unroll
        for (int r = 0; r < 4; r++) {
            int rr = rowbase + r;
            if (rr < N) out[(size_t)rr * HH + c * 16 + m16] = f2bf(acc[c][r]);
        }
    }
}

// ---------- CSR aggregation: 16 lanes/node, 4 nodes/wave, no reduction -----
// lane = qq*16 + c16: quarter qq owns node (blk*16 + wave*4 + qq); lane covers
// 8 cols (16B). Each lane walks ALL its node's edges (batches of 16, staged
// quarter-locally in LDS). Output h stored bf16.
__global__ __launch_bounds__(256) void k_agg(const ushort* __restrict__ xwb,
                                             const float* __restrict__ dinv,
                                             const int* __restrict__ rowptr,
                                             const uint2* __restrict__ edata,
                                             const float* __restrict__ b,
                                             const float* __restrict__ g,
                                             const float* __restrict__ beta,
                                             const float* __restrict__ m,
                                             const float* __restrict__ v,
                                             ushort* __restrict__ out,
                                             int N, int mode) {
    __shared__ uint  sS[256];
    __shared__ float sD[256];
    int wave = threadIdx.x >> 6;
    int lane = threadIdx.x & 63;
    int qq  = lane >> 4;
    int c16 = lane & 15;
    int n  = blockIdx.x * 16 + wave * 4 + qq;
    int nc = min(n, N - 1);
    int wb = wave * 64 + qq * 16;

    int beg = rowptr[nc];
    int end = rowptr[nc + 1];
    float di = dinv[nc];
    const char* xb = (const char*)xwb;
    uint coff = (uint)c16 << 4;      // byte offset within 256B row

    float acc[8];
    {
        uint4 w = *(const uint4*)(xb + (((uint)nc << 8) | coff));   // self row
        acc[0] = di * bfLo(w.x); acc[1] = di * bfHi(w.x);
        acc[2] = di * bfLo(w.y); acc[3] = di * bfHi(w.y);
        acc[4] = di * bfLo(w.z); acc[5] = di * bfHi(w.z);
        acc[6] = di * bfLo(w.w); acc[7] = di * bfHi(w.w);
    }

    for (int b2 = beg; b2 < end; b2 += 16) {
        int cnt = min(16, end - b2);
        if (c16 < cnt) {
            uint2 e = edata[b2 + c16];
            sS[wb + c16] = e.x << 8;
            sD[wb + c16] = __uint_as_float(e.y);
        }
        // same-wave LDS write->read (lgkmcnt ordered); no barrier needed
#pragma unroll 4
        for (int j = 0; j < cnt; j++) {
            uint so  = sS[wb + j];
            float dj = sD[wb + j];
            uint4 w = *(const uint4*)(xb + (so | coff));
            acc[0] = fmaf(dj, bfLo(w.x), acc[0]);
            acc[1] = fmaf(dj, bfHi(w.x), acc[1]);
            acc[2] = fmaf(dj, bfLo(w.y), acc[2]);
            acc[3] = fmaf(dj, bfHi(w.y), acc[3]);
            acc[4] = fmaf(dj, bfLo(w.z), acc[4]);
            acc[5] = fmaf(dj, bfHi(w.z), acc[5]);
            acc[6] = fmaf(dj, bfLo(w.w), acc[6]);
            acc[7] = fmaf(dj, bfHi(w.w), acc[7]);
        }
    }

    int colb = c16 * 8;
    float4 b0 = *(const float4*)(b + colb);
    float4 b1 = *(const float4*)(b + colb + 4);
    float val[8];
    val[0] = di * acc[0] + b0.x; val[1] = di * acc[1] + b0.y;
    val[2] = di * acc[2] + b0.z; val[3] = di * acc[3] + b0.w;
    val[4] = di * acc[4] + b1.x; val[5] = di * acc[5] + b1.y;
    val[6] = di * acc[6] + b1.z; val[7] = di * acc[7] + b1.w;
    if (mode) {
#pragma unroll
        for (int half = 0; half < 2; half++) {
            float4 mm = *(const float4*)(m + colb + half * 4);
            float4 vv = *(const float4*)(v + colb + half * 4);
            float4 gg = *(const float4*)(g + colb + half * 4);
            float4 be = *(const float4*)(beta + colb + half * 4);
            int o = half * 4;
            val[o+0] = fmaxf((val[o+0] - mm.x) * rsqrtf(vv.x + BN_EPS) * gg.x + be.x, 0.f);
            val[o+1] = fmaxf((val[o+1] - mm.y) * rsqrtf(vv.y + BN_EPS) * gg.y + be.y, 0.f);
            val[o+2] = fmaxf((val[o+2] - mm.z) * rsqrtf(vv.z + BN_EPS) * gg.z + be.z, 0.f);
            val[o+3] = fmaxf((val[o+3] - mm.w) * rsqrtf(vv.w + BN_EPS) * gg.w + be.w, 0.f);
        }
    }
    if (n < N) {
        uint4 o;
        o.x = packbf(val[0], val[1]);
        o.y = packbf(val[2], val[3]);
        o.z = packbf(val[4], val[5]);
        o.w = packbf(val[6], val[7]);
        *(uint4*)((char*)out + (((uint)n << 8) | coff)) = o;
    }
}

// ---------- pool (bf16 h input) ----------
__global__ __launch_bounds__(128) void k_pool(const ushort* __restrict__ h,
                                              const int* __restrict__ batch,
                                              float* __restrict__ sums,
                                              float* __restrict__ cnts, int N) {
    int col = threadIdx.x;
    int n0 = blockIdx.x * 128;
    int n1 = min(n0 + 128, N);
    float acc = 0.0f;
    float cnt = 0.0f;
    int curg = batch[n0];
    for (int n = n0; n < n1; n++) {
        int gg = batch[n];
        if (gg != curg) {
            atomAddF(&sums[(size_t)curg * HH + col], acc);
            if (col == 0) atomAddF(&cnts[curg], cnt);
            acc = 0.0f; cnt = 0.0f; curg = gg;
        }
        acc += __uint_as_float(((uint)h[(size_t)n * HH + col]) << 16);
        cnt += 1.0f;
    }
    atomAddF(&sums[(size_t)curg * HH + col], acc);
    if (col == 0) atomAddF(&cnts[curg], cnt);
}

// ---------- classifier head ----------
__global__ __launch_bounds__(64) void k_cls(const float* __restrict__ sums,
                                            const float* __restrict__ cnts,
                                            const float* __restrict__ Wc1,
                                            const float* __restrict__ bc1,
                                            const float* __restrict__ Wc2,
                                            const float* __restrict__ bc2,
                                            float* __restrict__ out, int Hc, int C) {
    int gI = blockIdx.x;
    int tid = threadIdx.x;
    __shared__ float pooled[HH];
    __shared__ float z[64];
    float cnt = fmaxf(cnts[gI], 1.0f);
    for (int c = tid; c < HH; c += 64) pooled[c] = sums[(size_t)gI * HH + c] / cnt;
    __syncthreads();
    if (tid < Hc) {
        float a = bc1[tid];
        for (int k = 0; k < HH; k++) a += pooled[k] * Wc1[k * Hc + tid];
        z[tid] = fmaxf(a, 0.0f);
    }
    __syncthreads();
    if (tid < C) {
        float a = bc2[tid];
        for (int k = 0; k < Hc; k++) a += z[k] * Wc2[k * C + tid];
        out[(size_t)gI * C + tid] = a;
    }
}

extern "C" void kernel_launch(void* const* d_in, const int* in_sizes, int n_in,
                              void* d_out, int out_size, void* d_ws, size_t ws_size,
                              hipStream_t stream) {
    const float* x     = (const float*)d_in[0];
    const int*   ei    = (const int*)d_in[1];
    const int*   batch = (const int*)d_in[2];
    const float* W1    = (const float*)d_in[3];
    const float* b1    = (const float*)d_in[4];
    const float* W2    = (const float*)d_in[5];
    const float* b2    = (const float*)d_in[6];
    const float* W3    = (const float*)d_in[7];
    const float* b3    = (const float*)d_in[8];
    const float* bn1_g = (const float*)d_in[9];
    const float* bn1_b = (const float*)d_in[10];
    const float* bn1_m = (const float*)d_in[11];
    const float* bn1_v = (const float*)d_in[12];
    const float* bn2_g = (const float*)d_in[13];
    const float* bn2_b = (const float*)d_in[14];
    const float* bn2_m = (const float*)d_in[15];
    const float* bn2_v = (const float*)d_in[16];
    const float* Wc1   = (const float*)d_in[17];
    const float* bc1   = (const float*)d_in[18];
    const float* Wc2   = (const float*)d_in[19];
    const float* bc2   = (const float*)d_in[20];
    float* out = (float*)d_out;

    const int N  = in_sizes[2];
    const int E  = in_sizes[1] / 2;
    const int K0 = in_sizes[0] / N;      // 256
    const int Hc = in_sizes[18];         // 64
    const int C  = in_sizes[20];         // 16
    const int G  = out_size / C;         // 64

    const int* srcv = ei;
    const int* dstv = ei + E;

    // workspace layout
    float* ws = (float*)d_ws;
    size_t NH = (size_t)N * HH;
    size_t Na = (((size_t)N + 255) / 256) * 256;
    size_t Ea = (((size_t)E + 255) / 256) * 256;
    ushort* bufA   = (ushort*)ws;            // N*128 bf16
    ushort* bufB   = (ushort*)(ws + NH);     // N*128 bf16
    float* dinv    = ws + 2 * NH;
    int*   degInt  = (int*)(dinv + Na);
    int*   rowptr  = degInt + Na;
    uint2* edata   = (uint2*)(rowptr + Na + 256);  // E * 8B
    uint2* bucketed= edata + Ea;                   // E * 8B
    int*   gH      = (int*)(bucketed + Ea);
    int*   gC      = gH + 65536;
    int*   totals  = gC + 65536;
    int*   baseArr = totals + 256;
    int*   partials= baseArr + 512;
    float* sums    = (float*)(partials + 256);
    float* cnts    = sums + (size_t)G * HH;
    uint*  Wp1     = (uint*)(cnts + 256);
    uint*  Wp2     = Wp1 + (size_t)K0 * HH;
    uint*  Wp3     = Wp2 + (size_t)HH * HH;

    int tile = (E + 255) / 256;
    int nb   = (int)((N + 255) / 256);
    int gGemm = (N + 63) / 64;
    int gAgg  = (N + 15) / 16;
    int gPool = (N + 127) / 128;

    // ---- CSR build (no global atomics) ----
    k_ahist<<<256, 256, 0, stream>>>(dstv, gH, E, tile);
    k_scan1<<<256, 256, 0, stream>>>(gH, gC, totals);
    k_scan2<<<1, 256, 0, stream>>>(totals, baseArr);
    k_asc<<<256, 256, 0, stream>>>(srcv, dstv, gC, baseArr, bucketed, E, tile);
    k_bdeg<<<256, 256, 0, stream>>>(bucketed, baseArr, degInt, dinv, N);
    k_scanA<<<nb, 256, 0, stream>>>(degInt, partials, N);
    k_scanB<<<1, 256, 0, stream>>>(partials, nb);
    k_scanC<<<nb, 256, 0, stream>>>(degInt, partials, rowptr, N);
    k_csc<<<256, 256, 0, stream>>>(bucketed, baseArr, rowptr, dinv, edata, N);

    // ---- weight splits ----
    k_wsplit<<<(128 * (K0 / 2) + 255) / 256, 256, 0, stream>>>(W1, Wp1, K0);
    k_wsplit<<<(128 * (HH / 2) + 255) / 256, 256, 0, stream>>>(W2, Wp2, HH);
    k_wsplit<<<(128 * (HH / 2) + 255) / 256, 256, 0, stream>>>(W3, Wp3, HH);

    // ---- layer 1 (fp32 A, 3-term) ----
    if (K0 == 256)
        k_gemm_mfma<8><<<gGemm, 256, 0, stream>>>(x, Wp1, bufA, N);
    else
        k_gemm_mfma<4><<<gGemm, 256, 0, stream>>>(x, Wp1, bufA, N);
    k_agg<<<gAgg, 256, 0, stream>>>(bufA, dinv, rowptr, edata, b1,
                                    bn1_g, bn1_b, bn1_m, bn1_v, bufB, N, 1);
    // ---- layer 2 (bf16 A, 2-term) ----
    k_gemm_bf<4><<<gGemm, 256, 0, stream>>>(bufB, Wp2, bufA, N);
    k_agg<<<gAgg, 256, 0, stream>>>(bufA, dinv, rowptr, edata, b2,
                                    bn2_g, bn2_b, bn2_m, bn2_v, bufB, N, 1);
    // ---- layer 3 (bf16 A, 2-term) ----
    k_gemm_bf<4><<<gGemm, 256, 0, stream>>>(bufB, Wp3, bufA, N);
    k_agg<<<gAgg, 256, 0, stream>>>(bufA, dinv, rowptr, edata, b3,
                                    nullptr, nullptr, nullptr, nullptr, bufB, N, 0);

    // ---- pool + classifier ----
    hipMemsetAsync(sums, 0, ((size_t)G * HH + G) * sizeof(float), stream);
    k_pool<<<gPool, 128, 0, stream>>>(bufB, batch, sums, cnts, N);
    k_cls<<<G, 64, 0, stream>>>(sums, cnts, Wc1, bc1, Wc2, bc2, out, Hc, C);
}